// Round 12
// baseline (1347.557 us; speedup 1.0000x reference)
//
#include <hip/hip_runtime.h>
#include <cstdint>

#define NBATCH 4096
#define NNODE  64
#define FEAT   32
#define H      128
#define NE     4
#define NL     3

typedef __attribute__((ext_vector_type(8))) short short8;
typedef __attribute__((ext_vector_type(4))) short short4v;
typedef __attribute__((ext_vector_type(4))) float f32x4;
typedef __attribute__((ext_vector_type(2))) float f32x2;
typedef unsigned long long u64;
typedef unsigned short ushort;

#define IMG_GC_ELEMS   (128 * 64)
#define IMG_GRU_ELEMS  (48 * 128)
#define IMG_GC_BYTES   (24 * IMG_GC_ELEMS * 2)
#define IMG_GRU_BYTES  (16 * IMG_GRU_ELEMS * 2)
#define WS_W_BYTES     (IMG_GC_BYTES + IMG_GRU_BYTES)
#define WIMG_SHORTS    (WS_W_BYTES / 2)
#define ADJ_IMG_ELEMS  4096
#define WS_FULL ((size_t)WS_W_BYTES + (size_t)NBATCH * NE * ADJ_IMG_ELEMS * 2)

__device__ __forceinline__ ushort f2b(float f) {
  union { float f; unsigned u; } v; v.f = f;
  unsigned u = v.u + 0x7FFFu + ((v.u >> 16) & 1u);
  return (ushort)(u >> 16);
}
__device__ __forceinline__ float b2f(ushort s) {
  union { unsigned u; float f; } v; v.u = ((unsigned)s) << 16;
  return v.f;
}
__device__ __forceinline__ unsigned cvtpk(float lo, float hi) {
  unsigned r;
  asm volatile("v_cvt_pk_bf16_f32 %0, %1, %2" : "=v"(r) : "v"(lo), "v"(hi));
  return r;
}
__device__ __forceinline__ u64 pk4(float a, float b, float c, float d) {
  return (u64)cvtpk(a, b) | ((u64)cvtpk(c, d) << 32);
}
__device__ __forceinline__ float sigm(float v) { return 1.0f / (1.0f + __expf(-v)); }
__device__ __forceinline__ float tanh_(float v) {
  v = fminf(fmaxf(v, -15.f), 15.f);
  float e = __expf(-2.f * v);
  return (1.f - e) / (1.f + e);
}
__device__ __forceinline__ int gidx128(int r, int g) { return r * 128 + ((g ^ (r & 7)) << 3); }
__device__ __forceinline__ int idx128(int r, int k) { return gidx128(r, k >> 3) + (k & 7); }
__device__ __forceinline__ int gidx64(int r, int g) { return r * 64 + (((g ^ (r & 7)) & 7) << 3); }

__device__ __forceinline__ short8 pack8f(const float* v) {
  union { unsigned u[4]; short8 s; } r;
  r.u[0] = cvtpk(v[0], v[1]); r.u[1] = cvtpk(v[2], v[3]);
  r.u[2] = cvtpk(v[4], v[5]); r.u[3] = cvtpk(v[6], v[7]);
  return r.s;
}

__device__ __forceinline__ void gll16(const void* g, void* l) {
  __builtin_amdgcn_global_load_lds(
      (const __attribute__((address_space(1))) unsigned int*)g,
      (__attribute__((address_space(3))) unsigned int*)l, 16, 0, 0);
}

// 4-wave stage: NIT * 4KB
#define STAGE(dst, src, NIT)                                             \
  do {                                                                   \
    _Pragma("unroll")                                                    \
    for (int it_ = 0; it_ < (NIT); ++it_) {                              \
      int off_ = (it_ * 4 + w) * 1024;                                   \
      gll16((const char*)(src) + off_ + lane * 16, (char*)(dst) + off_); \
    }                                                                    \
  } while (0)

#define MFMA16(A, B, C) __builtin_amdgcn_mfma_f32_16x16x32_bf16((A), (B), (C), 0, 0, 0)
// direct 16B fragment load from a weight image (L2-hot, shared across blocks)
#define GFRAG(base, off) (*(const short8*)&(base)[(off)])

// ============ K0: bf16 weight images (swizzled byte order; unchanged) ========
__global__ __launch_bounds__(256, 2) void k_prep(
    const float* __restrict__ gc_w, const float* __restrict__ w_ih,
    const float* __restrict__ w_hh, ushort* __restrict__ ws)
{
  const int t = threadIdx.x;
  if (blockIdx.x < 24) {
    const int blk = blockIdx.x;
    const int kh = blk & 1, e = (blk >> 1) & 3, l = blk >> 3;
    const float* We = gc_w + (size_t)(l * NE + e) * H * H;
    ushort* dst = ws + (size_t)blk * IMG_GC_ELEMS;
    #pragma unroll
    for (int it = 0; it < 4; ++it) {
      int idx = t + it * 256;
      int r = idx >> 3, g = idx & 7;
      float v[8];
      #pragma unroll
      for (int j = 0; j < 8; ++j) v[j] = We[(kh * 64 + g * 8 + j) * H + r];
      *(short8*)&dst[gidx64(r, g)] = pack8f(v);
    }
  } else {
    const int blk = blockIdx.x - 24;
    const int c = blk & 7, m = blk >> 3;
    const float* Mat = m ? w_hh : w_ih;
    ushort* dst = ws + WIMG_SHORTS - IMG_GRU_BYTES / 2 + (size_t)blk * IMG_GRU_ELEMS;
    #pragma unroll
    for (int it = 0; it < 3; ++it) {
      int idx = t + it * 256;
      int rr = idx >> 4, g = idx & 15;
      int mrow = (rr >> 4) * H + 16 * c + (rr & 15);
      float v[8];
      #pragma unroll
      for (int j = 0; j < 8; ++j) v[j] = Mat[mrow * H + g * 8 + j];
      *(short8*)&dst[gidx128(rr, g)] = pack8f(v);
    }
  }
}

// ============ K1: input embedding -> bf16 h0 tails; adj->bf16 images (unchanged) ======
template <bool ADJIMG>
__global__ __launch_bounds__(256, 2) void k_inemb(
    const float* __restrict__ x, const float* __restrict__ in_w,
    const float* __restrict__ in_b, const float* __restrict__ adj,
    ushort* __restrict__ ws, float* __restrict__ out)
{
  __shared__ float s_wt[FEAT * H];
  __shared__ float s_x[64 * FEAT];
  const int t = threadIdx.x;
  const int n = blockIdx.x >> 6, bt = blockIdx.x & 63, b0 = bt * 64;
  const float* wsrc = in_w + (size_t)n * FEAT * H;
  #pragma unroll
  for (int it = 0; it < 4; ++it) {
    int i4 = t + it * 256;
    *(f32x4*)&s_wt[i4 * 4] = *(const f32x4*)&wsrc[i4 * 4];
  }
  {
    int r = t >> 2, q = t & 3;
    const float* xs = x + ((size_t)(b0 + r) * NNODE + n) * FEAT;
    *(f32x4*)&s_x[r * 32 + q * 8]     = *(const f32x4*)&xs[q * 8];
    *(f32x4*)&s_x[r * 32 + q * 8 + 4] = *(const f32x4*)&xs[q * 8 + 4];
  }
  __syncthreads();
  const int h2 = t & 63, rp = t >> 6;
  const float bi0 = in_b[n * H + 2 * h2], bi1 = in_b[n * H + 2 * h2 + 1];
  #pragma unroll 1
  for (int m = 0; m < 16; ++m) {
    int r = rp + 4 * m;
    float a0 = bi0, a1 = bi1;
    #pragma unroll
    for (int d = 0; d < 32; ++d) {
      float xv = s_x[r * 32 + d];
      f32x2 wv = *(const f32x2*)&s_wt[d * H + 2 * h2];
      a0 += xv * wv.x; a1 += xv * wv.y;
    }
    unsigned p = cvtpk(a0, a1);
    ushort* tail = (ushort*)(out + ((size_t)(b0 + r) * NNODE + n) * H + 64);
    *(unsigned*)(tail + 2 * h2) = p;
  }
  if (ADJIMG) {
    const float* ab = adj + (size_t)blockIdx.x * NE * NNODE * NNODE;
    ushort* dst = ws + WIMG_SHORTS + (size_t)blockIdx.x * NE * ADJ_IMG_ELEMS;
    #pragma unroll 1
    for (int q = 0; q < 8; ++q) {
      int gi = t + q * 256;
      int e = gi >> 9, idx = gi & 511, r = idx >> 3, g = idx & 7;
      const float* src = ab + e * 4096 + r * 64 + g * 8;
      float v[8];
      #pragma unroll
      for (int j = 0; j < 8; ++j) v[j] = src[j];
      *(short8*)&dst[e * ADJ_IMG_ELEMS + gidx64(r, g)] = pack8f(v);
    }
  }
}

// ================= K2: weights direct-from-L2, 29KB LDS, 4 blocks/CU =============
template <bool ADJIMG>
__global__ __launch_bounds__(256, 4) void k_main(
    const float* __restrict__ adj,
    const float* __restrict__ gc_b,
    const float* __restrict__ b_ih, const float* __restrict__ b_hh,
    const ushort* __restrict__ wimg,
    float* __restrict__ out)
{
  __shared__ ushort s_u[8192];     // 16KB: S^T [h][n] gidx64 / xf [n][h] gidx128
  __shared__ ushort s_adj[4096];   // 8KB
  __shared__ float  s_bias[1280];  // gc_b slice | b_ih | b_hh

  const int t = threadIdx.x, b = blockIdx.x;
  const int w = t >> 6, lane = t & 63, lr = lane & 15, lq = lane >> 4;
  const int wm = w & 1, wn = w >> 1;
  float* outb = out + (size_t)b * NNODE * H;
  const ushort* img_gru = wimg + WIMG_SHORTS - IMG_GRU_BYTES / 2;
  const ushort* aimg = wimg + WIMG_SHORTS + (size_t)b * NE * ADJ_IMG_ELEMS;

  // ---- prologue: hidden h0 -> regs; GRU biases -> LDS ----
  short8 cur[2][4];   // rows 32*wm + 16*mt + lr; cols 32*ks + 8*lq
  #pragma unroll
  for (int mt = 0; mt < 2; ++mt)
    #pragma unroll
    for (int ks = 0; ks < 4; ++ks)
      cur[mt][ks] = *(const short8*)((const ushort*)(outb + (size_t)(32 * wm + 16 * mt + lr) * H + 64) + 32 * ks + 8 * lq);
  #pragma unroll
  for (int it = 0; it < 3; ++it) {
    int idx = t + it * 256;
    s_bias[512 + idx] = (idx < 384) ? b_ih[idx] : b_hh[idx - 384];
  }
  __syncthreads();

  #pragma unroll 1
  for (int layer = 0; layer < NL; ++layer) {
    f32x4 agg[2][4];
    #pragma unroll
    for (int mt = 0; mt < 2; ++mt)
      #pragma unroll
      for (int nt = 0; nt < 4; ++nt) agg[mt][nt] = f32x4{0.f, 0.f, 0.f, 0.f};

    // ======== edges: 2 barriers each; weights straight from L2 ====
    #pragma unroll 1
    for (int e = 0; e < NE; ++e) {
      const ushort* img_e = wimg + (size_t)((layer * NE + e) * 2) * IMG_GC_ELEMS;
      if (e == 0) {
        s_bias[t]       = gc_b[layer * 512 + t];
        s_bias[t + 256] = gc_b[layer * 512 + t + 256];
      }
      if (ADJIMG) {
        STAGE(s_adj, aimg + (size_t)e * ADJ_IMG_ELEMS, 2);
      } else {
        const float* adj_e = adj + (((size_t)b * NE + e) * NNODE * NNODE);
        #pragma unroll
        for (int it = 0; it < 2; ++it) {
          int idx = t + it * 256;
          int i = idx >> 3, g = idx & 7;
          const float* src = adj_e + i * 64 + g * 8;
          float v[8];
          #pragma unroll
          for (int j = 0; j < 8; ++j) v[j] = src[j];
          *(short8*)&s_adj[gidx64(i, g)] = pack8f(v);
        }
      }
      // ---- mm1: S = cur @ W_e, B-frags direct from image ----
      f32x4 Sacc[2][4];
      #pragma unroll
      for (int mt = 0; mt < 2; ++mt)
        #pragma unroll
        for (int nt = 0; nt < 4; ++nt) Sacc[mt][nt] = f32x4{0.f, 0.f, 0.f, 0.f};
      __builtin_amdgcn_s_setprio(1);
      #pragma unroll
      for (int kh = 0; kh < 2; ++kh) {
        const ushort* wb = img_e + (size_t)kh * IMG_GC_ELEMS;
        #pragma unroll
        for (int ks = 0; ks < 2; ++ks) {
          #pragma unroll
          for (int nt = 0; nt < 4; ++nt) {
            short8 bb = GFRAG(wb, gidx64(64 * wn + 16 * nt + lr, ks * 4 + lq));
            #pragma unroll
            for (int mt = 0; mt < 2; ++mt)
              Sacc[mt][nt] = MFMA16(cur[mt][2 * kh + ks], bb, Sacc[mt][nt]);
          }
        }
      }
      __builtin_amdgcn_s_setprio(0);
      // pack S^T -> s_u [h][n]
      #pragma unroll
      for (int mt = 0; mt < 2; ++mt) {
        int j0 = 32 * wm + 16 * mt + 4 * lq;
        #pragma unroll
        for (int nt = 0; nt < 4; ++nt) {
          int h = 64 * wn + 16 * nt + lr;
          *(u64*)&s_u[gidx64(h, j0 >> 3) + (j0 & 7)] =
              pk4(Sacc[mt][nt][0], Sacc[mt][nt][1], Sacc[mt][nt][2], Sacc[mt][nt][3]);
        }
      }
      __syncthreads();   // S^T + s_adj visible (drains everything; overlapped by 4 blocks/CU)

      // ---- mm2: O = adj_e @ S; agg += relu ----
      {
        f32x4 Oacc[2][4];
        #pragma unroll
        for (int mt = 0; mt < 2; ++mt)
          #pragma unroll
          for (int nt = 0; nt < 4; ++nt) Oacc[mt][nt] = f32x4{0.f, 0.f, 0.f, 0.f};
        __builtin_amdgcn_s_setprio(1);
        #pragma unroll
        for (int ks = 0; ks < 2; ++ks) {
          short8 a[2];
          #pragma unroll
          for (int mt = 0; mt < 2; ++mt)
            a[mt] = *(const short8*)&s_adj[gidx64(32 * wm + 16 * mt + lr, ks * 4 + lq)];
          #pragma unroll
          for (int nt = 0; nt < 4; ++nt) {
            short8 bb = *(const short8*)&s_u[gidx64(64 * wn + 16 * nt + lr, ks * 4 + lq)];
            #pragma unroll
            for (int mt = 0; mt < 2; ++mt)
              Oacc[mt][nt] = MFMA16(a[mt], bb, Oacc[mt][nt]);
          }
        }
        __builtin_amdgcn_s_setprio(0);
        #pragma unroll
        for (int mt = 0; mt < 2; ++mt)
          #pragma unroll
          for (int nt = 0; nt < 4; ++nt) {
            float bias = s_bias[e * 128 + 64 * wn + 16 * nt + lr];
            #pragma unroll
            for (int r = 0; r < 4; ++r)
              agg[mt][nt][r] += 0.25f * fmaxf(Oacc[mt][nt][r] + bias, 0.f);
          }
      }
      __syncthreads();   // close s_u / s_adj reads before next edge overwrites
    }  // edges

    // ---- XF: agg -> s_u as xf [node][h] ----
    #pragma unroll
    for (int mt = 0; mt < 2; ++mt)
      #pragma unroll
      for (int nt = 0; nt < 4; ++nt) {
        int h = 64 * wn + 16 * nt + lr;
        #pragma unroll
        for (int r = 0; r < 4; ++r)
          s_u[idx128(32 * wm + 16 * mt + 4 * lq + r, h)] = f2b(agg[mt][nt][r]);
      }
    __syncthreads();

    // ======== GRU: 4 pair-steps, ZERO barriers (no LDS writes) ========
    #pragma unroll 1
    for (int p = 0; p < 4; ++p) {
      const int cc = 2 * p + wn;
      const ushort* ihg = img_gru + (size_t)cc * IMG_GRU_ELEMS;
      const ushort* hhg = img_gru + (size_t)(8 + cc) * IMG_GRU_ELEMS;
      short4v holdv[2];
      #pragma unroll
      for (int nst = 0; nst < 2; ++nst)
        holdv[nst] = *(const short4v*)((const ushort*)(outb + (size_t)(16 * (2 * wm + nst) + lr) * H + 64) + 16 * cc + 4 * lq);
      f32x4 gi[3][2], gh[3][2];
      #pragma unroll
      for (int tg = 0; tg < 3; ++tg)
        #pragma unroll
        for (int nst = 0; nst < 2; ++nst) {
          gi[tg][nst] = f32x4{0.f, 0.f, 0.f, 0.f};
          gh[tg][nst] = f32x4{0.f, 0.f, 0.f, 0.f};
        }
      __builtin_amdgcn_s_setprio(1);
      #pragma unroll
      for (int ks = 0; ks < 4; ++ks) {
        short8 bb[2];
        #pragma unroll
        for (int nst = 0; nst < 2; ++nst)
          bb[nst] = *(const short8*)&s_u[gidx128(16 * (2 * wm + nst) + lr, ks * 4 + lq)];
        #pragma unroll
        for (int tg = 0; tg < 3; ++tg) {
          short8 a = GFRAG(ihg, gidx128(16 * tg + lr, ks * 4 + lq));
          #pragma unroll
          for (int nst = 0; nst < 2; ++nst)
            gi[tg][nst] = MFMA16(a, bb[nst], gi[tg][nst]);
        }
      }
      #pragma unroll
      for (int ks = 0; ks < 4; ++ks) {
        #pragma unroll
        for (int tg = 0; tg < 3; ++tg) {
          short8 a = GFRAG(hhg, gidx128(16 * tg + lr, ks * 4 + lq));
          #pragma unroll
          for (int nst = 0; nst < 2; ++nst)
            gh[tg][nst] = MFMA16(a, cur[nst][ks], gh[tg][nst]);
        }
      }
      __builtin_amdgcn_s_setprio(0);
      #pragma unroll
      for (int nst = 0; nst < 2; ++nst) {
        int node = 16 * (2 * wm + nst) + lr;
        float hf[4];
        #pragma unroll
        for (int r = 0; r < 4; ++r) {
          int mH = 16 * cc + 4 * lq + r;
          float rg = sigm(gi[0][nst][r] + s_bias[512 + mH] + gh[0][nst][r] + s_bias[896 + mH]);
          float zg = sigm(gi[1][nst][r] + s_bias[640 + mH] + gh[1][nst][r] + s_bias[1024 + mH]);
          float ng = tanh_(gi[2][nst][r] + s_bias[768 + mH] + rg * (gh[2][nst][r] + s_bias[1152 + mH]));
          hf[r] = (1.f - zg) * ng + zg * b2f((ushort)holdv[nst][r]);
        }
        *(u64*)((ushort*)(outb + (size_t)node * H + 64) + 16 * cc + 4 * lq) =
            pk4(hf[0], hf[1], hf[2], hf[3]);
      }
    }  // pairs
    __syncthreads();   // all h' stores drained + visible block-wide

    // ---- reload hidden regs from tails (block-private, L2-hot) ----
    if (layer < 2) {
      #pragma unroll
      for (int mt = 0; mt < 2; ++mt)
        #pragma unroll
        for (int ks = 0; ks < 4; ++ks)
          cur[mt][ks] = *(const short8*)((const ushort*)(outb + (size_t)(32 * wm + 16 * mt + lr) * H + 64) + 32 * ks + 8 * lq);
    }
  }  // layers
}

// ================= K3: output embedding + zero pad (unchanged) =============
__global__ __launch_bounds__(256, 2) void k_outemb(
    const float* __restrict__ out_w, const float* __restrict__ out_b,
    float* __restrict__ out)
{
  __shared__ float s_wt[H * FEAT];
  __shared__ float s_c[64 * 132];
  const int t = threadIdx.x;
  const int n = blockIdx.x >> 6, bt = blockIdx.x & 63, b0 = bt * 64;
  const float* wsrc = out_w + (size_t)n * H * FEAT;
  #pragma unroll
  for (int it = 0; it < 4; ++it) {
    int i4 = t + it * 256;
    *(f32x4*)&s_wt[i4 * 4] = *(const f32x4*)&wsrc[i4 * 4];
  }
  #pragma unroll
  for (int it = 0; it < 4; ++it) {
    int idx = t + it * 256;
    int r = idx >> 4, g = idx & 15;
    const ushort* tail = (const ushort*)(out + ((size_t)(b0 + r) * NNODE + n) * H + 64);
    short8 v = *(const short8*)(tail + g * 8);
    #pragma unroll
    for (int j = 0; j < 8; ++j) s_c[r * 132 + g * 8 + j] = b2f((ushort)v[j]);
  }
  __syncthreads();
  const int d = t & 31, rq = t >> 5;
  const float bias = out_b[n * FEAT + d];
  float accs[8];
  #pragma unroll
  for (int m = 0; m < 8; ++m) {
    int r = rq + 8 * m;
    float a = bias;
    #pragma unroll 8
    for (int k = 0; k < H; ++k) a += s_c[r * 132 + k] * s_wt[k * FEAT + d];
    accs[m] = a;
  }
  #pragma unroll
  for (int m = 0; m < 8; ++m) {
    int r = rq + 8 * m;
    out[((size_t)(b0 + r) * NNODE + n) * H + d] = accs[m];
  }
  #pragma unroll
  for (int q = 0; q < 6; ++q) {
    int idx = t + q * 256;
    int r = idx / 24, c4 = idx - r * 24;
    *(f32x4*)&out[((size_t)(b0 + r) * NNODE + n) * H + FEAT + c4 * 4] =
        f32x4{0.f, 0.f, 0.f, 0.f};
  }
}

extern "C" void kernel_launch(void* const* d_in, const int* in_sizes, int n_in,
                              void* d_out, int out_size, void* d_ws, size_t ws_size,
                              hipStream_t stream) {
  const float* x     = (const float*)d_in[0];
  const float* adj   = (const float*)d_in[1];
  const float* in_w  = (const float*)d_in[2];
  const float* in_b  = (const float*)d_in[3];
  const float* out_w = (const float*)d_in[4];
  const float* out_b = (const float*)d_in[5];
  const float* gc_w  = (const float*)d_in[6];
  const float* gc_b  = (const float*)d_in[7];
  const float* w_ih  = (const float*)d_in[8];
  const float* w_hh  = (const float*)d_in[9];
  const float* b_ih  = (const float*)d_in[10];
  const float* b_hh  = (const float*)d_in[11];
  (void)in_sizes; (void)n_in; (void)out_size;
  ushort* wimg = (ushort*)d_ws;
  const bool full = ws_size >= WS_FULL;
  hipLaunchKernelGGL(k_prep, dim3(40), dim3(256), 0, stream, gc_w, w_ih, w_hh, wimg);
  if (full) {
    hipLaunchKernelGGL(k_inemb<true>, dim3(NBATCH), dim3(256), 0, stream,
                       x, in_w, in_b, adj, wimg, (float*)d_out);
    hipLaunchKernelGGL(k_main<true>, dim3(NBATCH), dim3(256), 0, stream,
                       adj, gc_b, b_ih, b_hh, wimg, (float*)d_out);
  } else {
    hipLaunchKernelGGL(k_inemb<false>, dim3(NBATCH), dim3(256), 0, stream,
                       x, in_w, in_b, adj, wimg, (float*)d_out);
    hipLaunchKernelGGL(k_main<false>, dim3(NBATCH), dim3(256), 0, stream,
                       adj, gc_b, b_ih, b_hh, wimg, (float*)d_out);
  }
  hipLaunchKernelGGL(k_outemb, dim3(NBATCH), dim3(256), 0, stream, out_w, out_b, (float*)d_out);
}

// Round 13
// 854.026 us; speedup vs baseline: 1.5779x; 1.5779x over previous
//
#include <hip/hip_runtime.h>
#include <cstdint>

#define NBATCH 4096
#define NNODE  64
#define FEAT   32
#define H      128
#define NE     4
#define NL     3

typedef __attribute__((ext_vector_type(8))) short short8;
typedef __attribute__((ext_vector_type(4))) short short4v;
typedef __attribute__((ext_vector_type(4))) float f32x4;
typedef __attribute__((ext_vector_type(2))) float f32x2;
typedef unsigned long long u64;
typedef unsigned short ushort;

#define IMG_GC_ELEMS   (128 * 64)
#define IMG_GRU_ELEMS  (48 * 128)
#define IMG_GC_BYTES   (24 * IMG_GC_ELEMS * 2)
#define IMG_GRU_BYTES  (16 * IMG_GRU_ELEMS * 2)
#define WS_W_BYTES     (IMG_GC_BYTES + IMG_GRU_BYTES)
#define WIMG_SHORTS    (WS_W_BYTES / 2)
#define ADJ_IMG_ELEMS  4096
#define WS_FULL ((size_t)WS_W_BYTES + (size_t)NBATCH * NE * ADJ_IMG_ELEMS * 2)

__device__ __forceinline__ ushort f2b(float f) {
  union { float f; unsigned u; } v; v.f = f;
  unsigned u = v.u + 0x7FFFu + ((v.u >> 16) & 1u);
  return (ushort)(u >> 16);
}
__device__ __forceinline__ float b2f(ushort s) {
  union { unsigned u; float f; } v; v.u = ((unsigned)s) << 16;
  return v.f;
}
__device__ __forceinline__ unsigned cvtpk(float lo, float hi) {
  unsigned r;
  asm volatile("v_cvt_pk_bf16_f32 %0, %1, %2" : "=v"(r) : "v"(lo), "v"(hi));
  return r;
}
__device__ __forceinline__ u64 pk4(float a, float b, float c, float d) {
  return (u64)cvtpk(a, b) | ((u64)cvtpk(c, d) << 32);
}
__device__ __forceinline__ float sigm(float v) { return 1.0f / (1.0f + __expf(-v)); }
__device__ __forceinline__ float tanh_(float v) {
  v = fminf(fmaxf(v, -15.f), 15.f);
  float e = __expf(-2.f * v);
  return (1.f - e) / (1.f + e);
}
__device__ __forceinline__ int gidx128(int r, int g) { return r * 128 + ((g ^ (r & 7)) << 3); }
__device__ __forceinline__ int idx128(int r, int k) { return gidx128(r, k >> 3) + (k & 7); }
__device__ __forceinline__ int gidx64(int r, int g) { return r * 64 + (((g ^ (r & 7)) & 7) << 3); }

__device__ __forceinline__ short8 pack8f(const float* v) {
  union { unsigned u[4]; short8 s; } r;
  r.u[0] = cvtpk(v[0], v[1]); r.u[1] = cvtpk(v[2], v[3]);
  r.u[2] = cvtpk(v[4], v[5]); r.u[3] = cvtpk(v[6], v[7]);
  return r.s;
}

__device__ __forceinline__ void gll16(const void* g, void* l) {
  __builtin_amdgcn_global_load_lds(
      (const __attribute__((address_space(1))) unsigned int*)g,
      (__attribute__((address_space(3))) unsigned int*)l, 16, 0, 0);
}

// 4-wave stage: NIT * 4KB
#define STAGE(dst, src, NIT)                                             \
  do {                                                                   \
    _Pragma("unroll")                                                    \
    for (int it_ = 0; it_ < (NIT); ++it_) {                              \
      int off_ = (it_ * 4 + w) * 1024;                                   \
      gll16((const char*)(src) + off_ + lane * 16, (char*)(dst) + off_); \
    }                                                                    \
  } while (0)

#define MFMA16(A, B, C) __builtin_amdgcn_mfma_f32_16x16x32_bf16((A), (B), (C), 0, 0, 0)
// direct 16B fragment load from a weight image (L1/L2-hot, shared across blocks)
#define GFRAG(base, off) (*(const short8*)&(base)[(off)])

// ============ K0: bf16 weight images (swizzled byte order; unchanged) ========
__global__ __launch_bounds__(256, 2) void k_prep(
    const float* __restrict__ gc_w, const float* __restrict__ w_ih,
    const float* __restrict__ w_hh, ushort* __restrict__ ws)
{
  const int t = threadIdx.x;
  if (blockIdx.x < 24) {
    const int blk = blockIdx.x;
    const int kh = blk & 1, e = (blk >> 1) & 3, l = blk >> 3;
    const float* We = gc_w + (size_t)(l * NE + e) * H * H;
    ushort* dst = ws + (size_t)blk * IMG_GC_ELEMS;
    #pragma unroll
    for (int it = 0; it < 4; ++it) {
      int idx = t + it * 256;
      int r = idx >> 3, g = idx & 7;
      float v[8];
      #pragma unroll
      for (int j = 0; j < 8; ++j) v[j] = We[(kh * 64 + g * 8 + j) * H + r];
      *(short8*)&dst[gidx64(r, g)] = pack8f(v);
    }
  } else {
    const int blk = blockIdx.x - 24;
    const int c = blk & 7, m = blk >> 3;
    const float* Mat = m ? w_hh : w_ih;
    ushort* dst = ws + WIMG_SHORTS - IMG_GRU_BYTES / 2 + (size_t)blk * IMG_GRU_ELEMS;
    #pragma unroll
    for (int it = 0; it < 3; ++it) {
      int idx = t + it * 256;
      int rr = idx >> 4, g = idx & 15;
      int mrow = (rr >> 4) * H + 16 * c + (rr & 15);
      float v[8];
      #pragma unroll
      for (int j = 0; j < 8; ++j) v[j] = Mat[mrow * H + g * 8 + j];
      *(short8*)&dst[gidx128(rr, g)] = pack8f(v);
    }
  }
}

// ============ K1: input embedding -> bf16 h0 tails; adj->bf16 images (unchanged) ======
template <bool ADJIMG>
__global__ __launch_bounds__(256, 2) void k_inemb(
    const float* __restrict__ x, const float* __restrict__ in_w,
    const float* __restrict__ in_b, const float* __restrict__ adj,
    ushort* __restrict__ ws, float* __restrict__ out)
{
  __shared__ float s_wt[FEAT * H];
  __shared__ float s_x[64 * FEAT];
  const int t = threadIdx.x;
  const int n = blockIdx.x >> 6, bt = blockIdx.x & 63, b0 = bt * 64;
  const float* wsrc = in_w + (size_t)n * FEAT * H;
  #pragma unroll
  for (int it = 0; it < 4; ++it) {
    int i4 = t + it * 256;
    *(f32x4*)&s_wt[i4 * 4] = *(const f32x4*)&wsrc[i4 * 4];
  }
  {
    int r = t >> 2, q = t & 3;
    const float* xs = x + ((size_t)(b0 + r) * NNODE + n) * FEAT;
    *(f32x4*)&s_x[r * 32 + q * 8]     = *(const f32x4*)&xs[q * 8];
    *(f32x4*)&s_x[r * 32 + q * 8 + 4] = *(const f32x4*)&xs[q * 8 + 4];
  }
  __syncthreads();
  const int h2 = t & 63, rp = t >> 6;
  const float bi0 = in_b[n * H + 2 * h2], bi1 = in_b[n * H + 2 * h2 + 1];
  #pragma unroll 1
  for (int m = 0; m < 16; ++m) {
    int r = rp + 4 * m;
    float a0 = bi0, a1 = bi1;
    #pragma unroll
    for (int d = 0; d < 32; ++d) {
      float xv = s_x[r * 32 + d];
      f32x2 wv = *(const f32x2*)&s_wt[d * H + 2 * h2];
      a0 += xv * wv.x; a1 += xv * wv.y;
    }
    unsigned p = cvtpk(a0, a1);
    ushort* tail = (ushort*)(out + ((size_t)(b0 + r) * NNODE + n) * H + 64);
    *(unsigned*)(tail + 2 * h2) = p;
  }
  if (ADJIMG) {
    const float* ab = adj + (size_t)blockIdx.x * NE * NNODE * NNODE;
    ushort* dst = ws + WIMG_SHORTS + (size_t)blockIdx.x * NE * ADJ_IMG_ELEMS;
    #pragma unroll 1
    for (int q = 0; q < 8; ++q) {
      int gi = t + q * 256;
      int e = gi >> 9, idx = gi & 511, r = idx >> 3, g = idx & 7;
      const float* src = ab + e * 4096 + r * 64 + g * 8;
      float v[8];
      #pragma unroll
      for (int j = 0; j < 8; ++j) v[j] = src[j];
      *(short8*)&dst[e * ADJ_IMG_ELEMS + gidx64(r, g)] = pack8f(v);
    }
  }
}

// ================= K2: weights direct-from-L2, 29KB LDS =============
// __launch_bounds__ 2nd arg: empirical VGPR cap = 256/arg (R9/R10/R12).
// arg=2 -> 128 VGPR cap; actual ~110 -> 4 waves/SIMD -> 4 blocks/CU via LDS.
template <bool ADJIMG>
__global__ __launch_bounds__(256, 2) void k_main(
    const float* __restrict__ adj,
    const float* __restrict__ gc_b,
    const float* __restrict__ b_ih, const float* __restrict__ b_hh,
    const ushort* __restrict__ wimg,
    float* __restrict__ out)
{
  __shared__ ushort s_u[8192];     // 16KB: S^T [h][n] gidx64 / xf [n][h] gidx128
  __shared__ ushort s_adj[4096];   // 8KB
  __shared__ float  s_bias[1280];  // gc_b slice | b_ih | b_hh

  const int t = threadIdx.x, b = blockIdx.x;
  const int w = t >> 6, lane = t & 63, lr = lane & 15, lq = lane >> 4;
  const int wm = w & 1, wn = w >> 1;
  float* outb = out + (size_t)b * NNODE * H;
  const ushort* img_gru = wimg + WIMG_SHORTS - IMG_GRU_BYTES / 2;
  const ushort* aimg = wimg + WIMG_SHORTS + (size_t)b * NE * ADJ_IMG_ELEMS;

  // ---- prologue: hidden h0 -> regs; GRU biases -> LDS ----
  short8 cur[2][4];   // rows 32*wm + 16*mt + lr; cols 32*ks + 8*lq
  #pragma unroll
  for (int mt = 0; mt < 2; ++mt)
    #pragma unroll
    for (int ks = 0; ks < 4; ++ks)
      cur[mt][ks] = *(const short8*)((const ushort*)(outb + (size_t)(32 * wm + 16 * mt + lr) * H + 64) + 32 * ks + 8 * lq);
  #pragma unroll
  for (int it = 0; it < 3; ++it) {
    int idx = t + it * 256;
    s_bias[512 + idx] = (idx < 384) ? b_ih[idx] : b_hh[idx - 384];
  }
  __syncthreads();

  #pragma unroll 1
  for (int layer = 0; layer < NL; ++layer) {
    f32x4 agg[2][4];
    #pragma unroll
    for (int mt = 0; mt < 2; ++mt)
      #pragma unroll
      for (int nt = 0; nt < 4; ++nt) agg[mt][nt] = f32x4{0.f, 0.f, 0.f, 0.f};

    // ======== edges: 2 barriers each; weights straight from L2 ====
    #pragma unroll 1
    for (int e = 0; e < NE; ++e) {
      const ushort* img_e = wimg + (size_t)((layer * NE + e) * 2) * IMG_GC_ELEMS;
      if (e == 0) {
        s_bias[t]       = gc_b[layer * 512 + t];
        s_bias[t + 256] = gc_b[layer * 512 + t + 256];
      }
      if (ADJIMG) {
        STAGE(s_adj, aimg + (size_t)e * ADJ_IMG_ELEMS, 2);
      } else {
        const float* adj_e = adj + (((size_t)b * NE + e) * NNODE * NNODE);
        #pragma unroll
        for (int it = 0; it < 2; ++it) {
          int idx = t + it * 256;
          int i = idx >> 3, g = idx & 7;
          const float* src = adj_e + i * 64 + g * 8;
          float v[8];
          #pragma unroll
          for (int j = 0; j < 8; ++j) v[j] = src[j];
          *(short8*)&s_adj[gidx64(i, g)] = pack8f(v);
        }
      }
      // ---- mm1: S = cur @ W_e, B-frags direct from image ----
      f32x4 Sacc[2][4];
      #pragma unroll
      for (int mt = 0; mt < 2; ++mt)
        #pragma unroll
        for (int nt = 0; nt < 4; ++nt) Sacc[mt][nt] = f32x4{0.f, 0.f, 0.f, 0.f};
      __builtin_amdgcn_s_setprio(1);
      #pragma unroll
      for (int kh = 0; kh < 2; ++kh) {
        const ushort* wb = img_e + (size_t)kh * IMG_GC_ELEMS;
        #pragma unroll
        for (int ks = 0; ks < 2; ++ks) {
          #pragma unroll
          for (int nt = 0; nt < 4; ++nt) {
            short8 bb = GFRAG(wb, gidx64(64 * wn + 16 * nt + lr, ks * 4 + lq));
            #pragma unroll
            for (int mt = 0; mt < 2; ++mt)
              Sacc[mt][nt] = MFMA16(cur[mt][2 * kh + ks], bb, Sacc[mt][nt]);
          }
        }
      }
      __builtin_amdgcn_s_setprio(0);
      // pack S^T -> s_u [h][n]
      #pragma unroll
      for (int mt = 0; mt < 2; ++mt) {
        int j0 = 32 * wm + 16 * mt + 4 * lq;
        #pragma unroll
        for (int nt = 0; nt < 4; ++nt) {
          int h = 64 * wn + 16 * nt + lr;
          *(u64*)&s_u[gidx64(h, j0 >> 3) + (j0 & 7)] =
              pk4(Sacc[mt][nt][0], Sacc[mt][nt][1], Sacc[mt][nt][2], Sacc[mt][nt][3]);
        }
      }
      __syncthreads();   // S^T + s_adj visible

      // ---- mm2: O = adj_e @ S; agg += relu ----
      {
        f32x4 Oacc[2][4];
        #pragma unroll
        for (int mt = 0; mt < 2; ++mt)
          #pragma unroll
          for (int nt = 0; nt < 4; ++nt) Oacc[mt][nt] = f32x4{0.f, 0.f, 0.f, 0.f};
        __builtin_amdgcn_s_setprio(1);
        #pragma unroll
        for (int ks = 0; ks < 2; ++ks) {
          short8 a[2];
          #pragma unroll
          for (int mt = 0; mt < 2; ++mt)
            a[mt] = *(const short8*)&s_adj[gidx64(32 * wm + 16 * mt + lr, ks * 4 + lq)];
          #pragma unroll
          for (int nt = 0; nt < 4; ++nt) {
            short8 bb = *(const short8*)&s_u[gidx64(64 * wn + 16 * nt + lr, ks * 4 + lq)];
            #pragma unroll
            for (int mt = 0; mt < 2; ++mt)
              Oacc[mt][nt] = MFMA16(a[mt], bb, Oacc[mt][nt]);
          }
        }
        __builtin_amdgcn_s_setprio(0);
        #pragma unroll
        for (int mt = 0; mt < 2; ++mt)
          #pragma unroll
          for (int nt = 0; nt < 4; ++nt) {
            float bias = s_bias[e * 128 + 64 * wn + 16 * nt + lr];
            #pragma unroll
            for (int r = 0; r < 4; ++r)
              agg[mt][nt][r] += 0.25f * fmaxf(Oacc[mt][nt][r] + bias, 0.f);
          }
      }
      __syncthreads();   // close s_u / s_adj reads before next edge overwrites
    }  // edges

    // ---- XF: agg -> s_u as xf [node][h] ----
    #pragma unroll
    for (int mt = 0; mt < 2; ++mt)
      #pragma unroll
      for (int nt = 0; nt < 4; ++nt) {
        int h = 64 * wn + 16 * nt + lr;
        #pragma unroll
        for (int r = 0; r < 4; ++r)
          s_u[idx128(32 * wm + 16 * mt + 4 * lq + r, h)] = f2b(agg[mt][nt][r]);
      }
    __syncthreads();

    // ======== GRU: 4 pair-steps, ZERO barriers (no LDS writes) ========
    #pragma unroll 1
    for (int p = 0; p < 4; ++p) {
      const int cc = 2 * p + wn;
      const ushort* ihg = img_gru + (size_t)cc * IMG_GRU_ELEMS;
      const ushort* hhg = img_gru + (size_t)(8 + cc) * IMG_GRU_ELEMS;
      short4v holdv[2];
      #pragma unroll
      for (int nst = 0; nst < 2; ++nst)
        holdv[nst] = *(const short4v*)((const ushort*)(outb + (size_t)(16 * (2 * wm + nst) + lr) * H + 64) + 16 * cc + 4 * lq);
      f32x4 gi[3][2], gh[3][2];
      #pragma unroll
      for (int tg = 0; tg < 3; ++tg)
        #pragma unroll
        for (int nst = 0; nst < 2; ++nst) {
          gi[tg][nst] = f32x4{0.f, 0.f, 0.f, 0.f};
          gh[tg][nst] = f32x4{0.f, 0.f, 0.f, 0.f};
        }
      __builtin_amdgcn_s_setprio(1);
      #pragma unroll
      for (int ks = 0; ks < 4; ++ks) {
        short8 bb[2];
        #pragma unroll
        for (int nst = 0; nst < 2; ++nst)
          bb[nst] = *(const short8*)&s_u[gidx128(16 * (2 * wm + nst) + lr, ks * 4 + lq)];
        #pragma unroll
        for (int tg = 0; tg < 3; ++tg) {
          short8 a = GFRAG(ihg, gidx128(16 * tg + lr, ks * 4 + lq));
          #pragma unroll
          for (int nst = 0; nst < 2; ++nst)
            gi[tg][nst] = MFMA16(a, bb[nst], gi[tg][nst]);
        }
      }
      #pragma unroll
      for (int ks = 0; ks < 4; ++ks) {
        #pragma unroll
        for (int tg = 0; tg < 3; ++tg) {
          short8 a = GFRAG(hhg, gidx128(16 * tg + lr, ks * 4 + lq));
          #pragma unroll
          for (int nst = 0; nst < 2; ++nst)
            gh[tg][nst] = MFMA16(a, cur[nst][ks], gh[tg][nst]);
        }
      }
      __builtin_amdgcn_s_setprio(0);
      #pragma unroll
      for (int nst = 0; nst < 2; ++nst) {
        int node = 16 * (2 * wm + nst) + lr;
        float hf[4];
        #pragma unroll
        for (int r = 0; r < 4; ++r) {
          int mH = 16 * cc + 4 * lq + r;
          float rg = sigm(gi[0][nst][r] + s_bias[512 + mH] + gh[0][nst][r] + s_bias[896 + mH]);
          float zg = sigm(gi[1][nst][r] + s_bias[640 + mH] + gh[1][nst][r] + s_bias[1024 + mH]);
          float ng = tanh_(gi[2][nst][r] + s_bias[768 + mH] + rg * (gh[2][nst][r] + s_bias[1152 + mH]));
          hf[r] = (1.f - zg) * ng + zg * b2f((ushort)holdv[nst][r]);
        }
        *(u64*)((ushort*)(outb + (size_t)node * H + 64) + 16 * cc + 4 * lq) =
            pk4(hf[0], hf[1], hf[2], hf[3]);
      }
    }  // pairs
    __syncthreads();   // all h' stores drained + visible block-wide

    // ---- reload hidden regs from tails (block-private, L2-hot) ----
    if (layer < 2) {
      #pragma unroll
      for (int mt = 0; mt < 2; ++mt)
        #pragma unroll
        for (int ks = 0; ks < 4; ++ks)
          cur[mt][ks] = *(const short8*)((const ushort*)(outb + (size_t)(32 * wm + 16 * mt + lr) * H + 64) + 32 * ks + 8 * lq);
    }
  }  // layers
}

// ================= K3: output embedding + zero pad (unchanged) =============
__global__ __launch_bounds__(256, 2) void k_outemb(
    const float* __restrict__ out_w, const float* __restrict__ out_b,
    float* __restrict__ out)
{
  __shared__ float s_wt[H * FEAT];
  __shared__ float s_c[64 * 132];
  const int t = threadIdx.x;
  const int n = blockIdx.x >> 6, bt = blockIdx.x & 63, b0 = bt * 64;
  const float* wsrc = out_w + (size_t)n * H * FEAT;
  #pragma unroll
  for (int it = 0; it < 4; ++it) {
    int i4 = t + it * 256;
    *(f32x4*)&s_wt[i4 * 4] = *(const f32x4*)&wsrc[i4 * 4];
  }
  #pragma unroll
  for (int it = 0; it < 4; ++it) {
    int idx = t + it * 256;
    int r = idx >> 4, g = idx & 15;
    const ushort* tail = (const ushort*)(out + ((size_t)(b0 + r) * NNODE + n) * H + 64);
    short8 v = *(const short8*)(tail + g * 8);
    #pragma unroll
    for (int j = 0; j < 8; ++j) s_c[r * 132 + g * 8 + j] = b2f((ushort)v[j]);
  }
  __syncthreads();
  const int d = t & 31, rq = t >> 5;
  const float bias = out_b[n * FEAT + d];
  float accs[8];
  #pragma unroll
  for (int m = 0; m < 8; ++m) {
    int r = rq + 8 * m;
    float a = bias;
    #pragma unroll 8
    for (int k = 0; k < H; ++k) a += s_c[r * 132 + k] * s_wt[k * FEAT + d];
    accs[m] = a;
  }
  #pragma unroll
  for (int m = 0; m < 8; ++m) {
    int r = rq + 8 * m;
    out[((size_t)(b0 + r) * NNODE + n) * H + d] = accs[m];
  }
  #pragma unroll
  for (int q = 0; q < 6; ++q) {
    int idx = t + q * 256;
    int r = idx / 24, c4 = idx - r * 24;
    *(f32x4*)&out[((size_t)(b0 + r) * NNODE + n) * H + FEAT + c4 * 4] =
        f32x4{0.f, 0.f, 0.f, 0.f};
  }
}

extern "C" void kernel_launch(void* const* d_in, const int* in_sizes, int n_in,
                              void* d_out, int out_size, void* d_ws, size_t ws_size,
                              hipStream_t stream) {
  const float* x     = (const float*)d_in[0];
  const float* adj   = (const float*)d_in[1];
  const float* in_w  = (const float*)d_in[2];
  const float* in_b  = (const float*)d_in[3];
  const float* out_w = (const float*)d_in[4];
  const float* out_b = (const float*)d_in[5];
  const float* gc_w  = (const float*)d_in[6];
  const float* gc_b  = (const float*)d_in[7];
  const float* w_ih  = (const float*)d_in[8];
  const float* w_hh  = (const float*)d_in[9];
  const float* b_ih  = (const float*)d_in[10];
  const float* b_hh  = (const float*)d_in[11];
  (void)in_sizes; (void)n_in; (void)out_size;
  ushort* wimg = (ushort*)d_ws;
  const bool full = ws_size >= WS_FULL;
  hipLaunchKernelGGL(k_prep, dim3(40), dim3(256), 0, stream, gc_w, w_ih, w_hh, wimg);
  if (full) {
    hipLaunchKernelGGL(k_inemb<true>, dim3(NBATCH), dim3(256), 0, stream,
                       x, in_w, in_b, adj, wimg, (float*)d_out);
    hipLaunchKernelGGL(k_main<true>, dim3(NBATCH), dim3(256), 0, stream,
                       adj, gc_b, b_ih, b_hh, wimg, (float*)d_out);
  } else {
    hipLaunchKernelGGL(k_inemb<false>, dim3(NBATCH), dim3(256), 0, stream,
                       x, in_w, in_b, adj, wimg, (float*)d_out);
    hipLaunchKernelGGL(k_main<false>, dim3(NBATCH), dim3(256), 0, stream,
                       adj, gc_b, b_ih, b_hh, wimg, (float*)d_out);
  }
  hipLaunchKernelGGL(k_outemb, dim3(NBATCH), dim3(256), 0, stream, out_w, out_b, (float*)d_out);
}

// Round 14
// 775.376 us; speedup vs baseline: 1.7379x; 1.1014x over previous
//
#include <hip/hip_runtime.h>
#include <cstdint>

#define NBATCH 4096
#define NNODE  64
#define FEAT   32
#define H      128
#define NE     4
#define NL     3

typedef __attribute__((ext_vector_type(8))) short short8;
typedef __attribute__((ext_vector_type(4))) short short4v;
typedef __attribute__((ext_vector_type(4))) float f32x4;
typedef __attribute__((ext_vector_type(2))) float f32x2;
typedef unsigned long long u64;
typedef unsigned short ushort;

#define IMG_GC_ELEMS   (128 * 64)
#define IMG_GRU_ELEMS  (48 * 128)
#define IMG_GC_BYTES   (24 * IMG_GC_ELEMS * 2)
#define IMG_GRU_BYTES  (16 * IMG_GRU_ELEMS * 2)
#define WS_W_BYTES     (IMG_GC_BYTES + IMG_GRU_BYTES)
#define WIMG_SHORTS    (WS_W_BYTES / 2)
#define ADJ_IMG_ELEMS  4096
#define WS_FULL ((size_t)WS_W_BYTES + (size_t)NBATCH * NE * ADJ_IMG_ELEMS * 2)

__device__ __forceinline__ ushort f2b(float f) {
  union { float f; unsigned u; } v; v.f = f;
  unsigned u = v.u + 0x7FFFu + ((v.u >> 16) & 1u);
  return (ushort)(u >> 16);
}
__device__ __forceinline__ float b2f(ushort s) {
  union { unsigned u; float f; } v; v.u = ((unsigned)s) << 16;
  return v.f;
}
__device__ __forceinline__ unsigned cvtpk(float lo, float hi) {
  unsigned r;
  asm volatile("v_cvt_pk_bf16_f32 %0, %1, %2" : "=v"(r) : "v"(lo), "v"(hi));
  return r;
}
__device__ __forceinline__ u64 pk4(float a, float b, float c, float d) {
  return (u64)cvtpk(a, b) | ((u64)cvtpk(c, d) << 32);
}
__device__ __forceinline__ float sigm(float v) { return 1.0f / (1.0f + __expf(-v)); }
__device__ __forceinline__ float tanh_(float v) {
  v = fminf(fmaxf(v, -15.f), 15.f);
  float e = __expf(-2.f * v);
  return (1.f - e) / (1.f + e);
}
__device__ __forceinline__ int gidx128(int r, int g) { return r * 128 + ((g ^ (r & 7)) << 3); }
__device__ __forceinline__ int idx128(int r, int k) { return gidx128(r, k >> 3) + (k & 7); }
__device__ __forceinline__ int gidx64(int r, int g) { return r * 64 + (((g ^ (r & 7)) & 7) << 3); }

__device__ __forceinline__ short8 pack8f(const float* v) {
  union { unsigned u[4]; short8 s; } r;
  r.u[0] = cvtpk(v[0], v[1]); r.u[1] = cvtpk(v[2], v[3]);
  r.u[2] = cvtpk(v[4], v[5]); r.u[3] = cvtpk(v[6], v[7]);
  return r.s;
}

__device__ __forceinline__ void gll16(const void* g, void* l) {
  __builtin_amdgcn_global_load_lds(
      (const __attribute__((address_space(1))) unsigned int*)g,
      (__attribute__((address_space(3))) unsigned int*)l, 16, 0, 0);
}

// 4-wave stage: NIT * 4KB
#define STAGE(dst, src, NIT)                                             \
  do {                                                                   \
    _Pragma("unroll")                                                    \
    for (int it_ = 0; it_ < (NIT); ++it_) {                              \
      int off_ = (it_ * 4 + w) * 1024;                                   \
      gll16((const char*)(src) + off_ + lane * 16, (char*)(dst) + off_); \
    }                                                                    \
  } while (0)

#define BAR() do { asm volatile("s_waitcnt lgkmcnt(0)" ::: "memory"); \
                   __builtin_amdgcn_s_barrier(); } while (0)
#define VMW(N) do { asm volatile("s_waitcnt vmcnt(" #N ")" ::: "memory"); \
                    __builtin_amdgcn_sched_barrier(0); } while (0)
#define SB0() __builtin_amdgcn_sched_barrier(0)

#define MFMA16(A, B, C) __builtin_amdgcn_mfma_f32_16x16x32_bf16((A), (B), (C), 0, 0, 0)
// direct 16B fragment load from a weight image (L2-hot, shared across all blocks)
#define GFRAG(base, off) (*(const short8*)&(base)[(off)])

// ============ K0: bf16 weight images (swizzled byte order; unchanged) ========
__global__ __launch_bounds__(256, 2) void k_prep(
    const float* __restrict__ gc_w, const float* __restrict__ w_ih,
    const float* __restrict__ w_hh, ushort* __restrict__ ws)
{
  const int t = threadIdx.x;
  if (blockIdx.x < 24) {
    const int blk = blockIdx.x;
    const int kh = blk & 1, e = (blk >> 1) & 3, l = blk >> 3;
    const float* We = gc_w + (size_t)(l * NE + e) * H * H;
    ushort* dst = ws + (size_t)blk * IMG_GC_ELEMS;
    #pragma unroll
    for (int it = 0; it < 4; ++it) {
      int idx = t + it * 256;
      int r = idx >> 3, g = idx & 7;
      float v[8];
      #pragma unroll
      for (int j = 0; j < 8; ++j) v[j] = We[(kh * 64 + g * 8 + j) * H + r];
      *(short8*)&dst[gidx64(r, g)] = pack8f(v);
    }
  } else {
    const int blk = blockIdx.x - 24;
    const int c = blk & 7, m = blk >> 3;
    const float* Mat = m ? w_hh : w_ih;
    ushort* dst = ws + WIMG_SHORTS - IMG_GRU_BYTES / 2 + (size_t)blk * IMG_GRU_ELEMS;
    #pragma unroll
    for (int it = 0; it < 3; ++it) {
      int idx = t + it * 256;
      int rr = idx >> 4, g = idx & 15;
      int mrow = (rr >> 4) * H + 16 * c + (rr & 15);
      float v[8];
      #pragma unroll
      for (int j = 0; j < 8; ++j) v[j] = Mat[mrow * H + g * 8 + j];
      *(short8*)&dst[gidx128(rr, g)] = pack8f(v);
    }
  }
}

// ============ K1: input embedding -> bf16 h0 tails; adj->bf16 images (unchanged) ======
template <bool ADJIMG>
__global__ __launch_bounds__(256, 2) void k_inemb(
    const float* __restrict__ x, const float* __restrict__ in_w,
    const float* __restrict__ in_b, const float* __restrict__ adj,
    ushort* __restrict__ ws, float* __restrict__ out)
{
  __shared__ float s_wt[FEAT * H];
  __shared__ float s_x[64 * FEAT];
  const int t = threadIdx.x;
  const int n = blockIdx.x >> 6, bt = blockIdx.x & 63, b0 = bt * 64;
  const float* wsrc = in_w + (size_t)n * FEAT * H;
  #pragma unroll
  for (int it = 0; it < 4; ++it) {
    int i4 = t + it * 256;
    *(f32x4*)&s_wt[i4 * 4] = *(const f32x4*)&wsrc[i4 * 4];
  }
  {
    int r = t >> 2, q = t & 3;
    const float* xs = x + ((size_t)(b0 + r) * NNODE + n) * FEAT;
    *(f32x4*)&s_x[r * 32 + q * 8]     = *(const f32x4*)&xs[q * 8];
    *(f32x4*)&s_x[r * 32 + q * 8 + 4] = *(const f32x4*)&xs[q * 8 + 4];
  }
  __syncthreads();
  const int h2 = t & 63, rp = t >> 6;
  const float bi0 = in_b[n * H + 2 * h2], bi1 = in_b[n * H + 2 * h2 + 1];
  #pragma unroll 1
  for (int m = 0; m < 16; ++m) {
    int r = rp + 4 * m;
    float a0 = bi0, a1 = bi1;
    #pragma unroll
    for (int d = 0; d < 32; ++d) {
      float xv = s_x[r * 32 + d];
      f32x2 wv = *(const f32x2*)&s_wt[d * H + 2 * h2];
      a0 += xv * wv.x; a1 += xv * wv.y;
    }
    unsigned p = cvtpk(a0, a1);
    ushort* tail = (ushort*)(out + ((size_t)(b0 + r) * NNODE + n) * H + 64);
    *(unsigned*)(tail + 2 * h2) = p;
  }
  if (ADJIMG) {
    const float* ab = adj + (size_t)blockIdx.x * NE * NNODE * NNODE;
    ushort* dst = ws + WIMG_SHORTS + (size_t)blockIdx.x * NE * ADJ_IMG_ELEMS;
    #pragma unroll 1
    for (int q = 0; q < 8; ++q) {
      int gi = t + q * 256;
      int e = gi >> 9, idx = gi & 511, r = idx >> 3, g = idx & 7;
      const float* src = ab + e * 4096 + r * 64 + g * 8;
      float v[8];
      #pragma unroll
      for (int j = 0; j < 8; ++j) v[j] = src[j];
      *(short8*)&dst[e * ADJ_IMG_ELEMS + gidx64(r, g)] = pack8f(v);
    }
  }
}

// ================= K2: hybrid — R8 LDS-staged edges + R13 zero-barrier L2-direct GRU ====
template <bool ADJIMG>
__global__ __launch_bounds__(256, 2) void k_main(
    const float* __restrict__ adj,
    const float* __restrict__ gc_b,
    const float* __restrict__ b_ih, const float* __restrict__ b_hh,
    const ushort* __restrict__ wimg,
    float* __restrict__ out)
{
  __shared__ ushort s_w0[8192];    // 16KB  W dbuf A
  __shared__ ushort s_w1[8192];    // 16KB  W dbuf B
  __shared__ ushort s_adj[4096];   // 8KB
  __shared__ ushort s_u[8192];     // 16KB: S^T [h][n] gidx64 / xf [n][h] gidx128
  __shared__ float  s_bias[1280];  // gc_b slice | b_ih | b_hh

  const int t = threadIdx.x, b = blockIdx.x;
  const int w = t >> 6, lane = t & 63, lr = lane & 15, lq = lane >> 4;
  const int wm = w & 1, wn = w >> 1;
  float* outb = out + (size_t)b * NNODE * H;
  const ushort* img_gru = wimg + WIMG_SHORTS - IMG_GRU_BYTES / 2;
  const ushort* aimg = wimg + WIMG_SHORTS + (size_t)b * NE * ADJ_IMG_ELEMS;

  // ---- prologue: W0/W1 <- (L0,e0) kh0/kh1; hidden h0 -> regs; GRU biases ----
  STAGE(s_w0, wimg, 4);
  STAGE(s_w1, wimg + IMG_GC_ELEMS, 4);
  short8 cur[2][4];   // rows 32*wm + 16*mt + lr; cols 32*ks + 8*lq
  #pragma unroll
  for (int mt = 0; mt < 2; ++mt)
    #pragma unroll
    for (int ks = 0; ks < 4; ++ks)
      cur[mt][ks] = *(const short8*)((const ushort*)(outb + (size_t)(32 * wm + 16 * mt + lr) * H + 64) + 32 * ks + 8 * lq);
  #pragma unroll
  for (int it = 0; it < 3; ++it) {
    int idx = t + it * 256;
    s_bias[512 + idx] = (idx < 384) ? b_ih[idx] : b_hh[idx - 384];
  }
  __syncthreads();

  #pragma unroll 1
  for (int layer = 0; layer < NL; ++layer) {
    f32x4 agg[2][4];
    #pragma unroll
    for (int mt = 0; mt < 2; ++mt)
      #pragma unroll
      for (int nt = 0; nt < 4; ++nt) agg[mt][nt] = f32x4{0.f, 0.f, 0.f, 0.f};

    // ======== edges: R8 staged pipeline; ledger drains before publishing barrier ====
    // outstanding gll16 ledger (uniform/wave): P2 exit: W1next drained (VMW2, adj flies);
    // P3 exit: adj drained (VMW4, W0next flies); P4 exit: W0next drained (VMW4, W1next flies)
    #pragma unroll 1
    for (int e = 0; e < NE; ++e) {
      const ushort* img_e = wimg + (size_t)((layer * NE + e) * 2) * IMG_GC_ELEMS;

      // ---- P2: [e0: gc_b]; stage adj(e); mm1-kh0 (B from s_w0) ----
      if (e == 0) {
        s_bias[t]       = gc_b[layer * 512 + t];
        s_bias[t + 256] = gc_b[layer * 512 + t + 256];
      }
      if (ADJIMG) {
        STAGE(s_adj, aimg + (size_t)e * ADJ_IMG_ELEMS, 2);
        SB0();
      } else {
        const float* adj_e = adj + (((size_t)b * NE + e) * NNODE * NNODE);
        #pragma unroll
        for (int it = 0; it < 2; ++it) {
          int idx = t + it * 256;
          int i = idx >> 3, g = idx & 7;
          const float* src = adj_e + i * 64 + g * 8;
          float v[8];
          #pragma unroll
          for (int j = 0; j < 8; ++j) v[j] = src[j];
          *(short8*)&s_adj[gidx64(i, g)] = pack8f(v);
        }
      }
      f32x4 Sacc[2][4];
      #pragma unroll
      for (int mt = 0; mt < 2; ++mt)
        #pragma unroll
        for (int nt = 0; nt < 4; ++nt) Sacc[mt][nt] = f32x4{0.f, 0.f, 0.f, 0.f};
      __builtin_amdgcn_s_setprio(1);
      #pragma unroll
      for (int ks = 0; ks < 2; ++ks) {
        #pragma unroll
        for (int nt = 0; nt < 4; ++nt) {
          short8 bb = *(const short8*)&s_w0[gidx64(64 * wn + 16 * nt + lr, ks * 4 + lq)];
          #pragma unroll
          for (int mt = 0; mt < 2; ++mt)
            Sacc[mt][nt] = MFMA16(cur[mt][ks], bb, Sacc[mt][nt]);
        }
      }
      __builtin_amdgcn_s_setprio(0);
      if (ADJIMG) { VMW(2); BAR(); } else __syncthreads();   // W1(prev) drained; adj flies

      // ---- P3: stage W0<-kh0(e+1); mm1-kh1 (B from s_w1); pack S^T -> s_u ----
      if (e < 3) { STAGE(s_w0, img_e + 2 * IMG_GC_ELEMS, 4); SB0(); }
      __builtin_amdgcn_s_setprio(1);
      #pragma unroll
      for (int ks = 0; ks < 2; ++ks) {
        #pragma unroll
        for (int nt = 0; nt < 4; ++nt) {
          short8 bb = *(const short8*)&s_w1[gidx64(64 * wn + 16 * nt + lr, ks * 4 + lq)];
          #pragma unroll
          for (int mt = 0; mt < 2; ++mt)
            Sacc[mt][nt] = MFMA16(cur[mt][2 + ks], bb, Sacc[mt][nt]);
        }
      }
      __builtin_amdgcn_s_setprio(0);
      #pragma unroll
      for (int mt = 0; mt < 2; ++mt) {
        int j0 = 32 * wm + 16 * mt + 4 * lq;
        #pragma unroll
        for (int nt = 0; nt < 4; ++nt) {
          int h = 64 * wn + 16 * nt + lr;
          *(u64*)&s_u[gidx64(h, j0 >> 3) + (j0 & 7)] =
              pk4(Sacc[mt][nt][0], Sacc[mt][nt][1], Sacc[mt][nt][2], Sacc[mt][nt][3]);
        }
      }
      if (ADJIMG) { if (e < 3) { VMW(4); } else { VMW(0); } BAR(); } else __syncthreads();

      // ---- P4: stage W1<-kh1(e+1); mm2 (A=s_adj, B=s_u); agg += relu ----
      if (e < 3) { STAGE(s_w1, img_e + 3 * IMG_GC_ELEMS, 4); SB0(); }
      {
        f32x4 Oacc[2][4];
        #pragma unroll
        for (int mt = 0; mt < 2; ++mt)
          #pragma unroll
          for (int nt = 0; nt < 4; ++nt) Oacc[mt][nt] = f32x4{0.f, 0.f, 0.f, 0.f};
        __builtin_amdgcn_s_setprio(1);
        #pragma unroll
        for (int ks = 0; ks < 2; ++ks) {
          short8 a[2];
          #pragma unroll
          for (int mt = 0; mt < 2; ++mt)
            a[mt] = *(const short8*)&s_adj[gidx64(32 * wm + 16 * mt + lr, ks * 4 + lq)];
          #pragma unroll
          for (int nt = 0; nt < 4; ++nt) {
            short8 bb = *(const short8*)&s_u[gidx64(64 * wn + 16 * nt + lr, ks * 4 + lq)];
            #pragma unroll
            for (int mt = 0; mt < 2; ++mt)
              Oacc[mt][nt] = MFMA16(a[mt], bb, Oacc[mt][nt]);
          }
        }
        __builtin_amdgcn_s_setprio(0);
        #pragma unroll
        for (int mt = 0; mt < 2; ++mt)
          #pragma unroll
          for (int nt = 0; nt < 4; ++nt) {
            float bias = s_bias[e * 128 + 64 * wn + 16 * nt + lr];
            #pragma unroll
            for (int r = 0; r < 4; ++r)
              agg[mt][nt][r] += 0.25f * fmaxf(Oacc[mt][nt][r] + bias, 0.f);
          }
      }
      if (ADJIMG) { if (e < 3) { VMW(4); } BAR(); } else __syncthreads();  // W0next drained
    }  // edges

    // ---- XF: agg -> s_u as xf [node][h] ----
    #pragma unroll
    for (int mt = 0; mt < 2; ++mt)
      #pragma unroll
      for (int nt = 0; nt < 4; ++nt) {
        int h = 64 * wn + 16 * nt + lr;
        #pragma unroll
        for (int r = 0; r < 4; ++r)
          s_u[idx128(32 * wm + 16 * mt + 4 * lq + r, h)] = f2b(agg[mt][nt][r]);
      }
    __syncthreads();

    // ======== GRU: 4 pair-steps, ZERO barriers, weights direct from L2 (R13) ========
    #pragma unroll 1
    for (int p = 0; p < 4; ++p) {
      const int cc = 2 * p + wn;
      const ushort* ihg = img_gru + (size_t)cc * IMG_GRU_ELEMS;
      const ushort* hhg = img_gru + (size_t)(8 + cc) * IMG_GRU_ELEMS;
      short4v holdv[2];
      #pragma unroll
      for (int nst = 0; nst < 2; ++nst)
        holdv[nst] = *(const short4v*)((const ushort*)(outb + (size_t)(16 * (2 * wm + nst) + lr) * H + 64) + 16 * cc + 4 * lq);
      f32x4 gi[3][2], gh[3][2];
      #pragma unroll
      for (int tg = 0; tg < 3; ++tg)
        #pragma unroll
        for (int nst = 0; nst < 2; ++nst) {
          gi[tg][nst] = f32x4{0.f, 0.f, 0.f, 0.f};
          gh[tg][nst] = f32x4{0.f, 0.f, 0.f, 0.f};
        }
      __builtin_amdgcn_s_setprio(1);
      #pragma unroll
      for (int ks = 0; ks < 4; ++ks) {
        short8 bb[2];
        #pragma unroll
        for (int nst = 0; nst < 2; ++nst)
          bb[nst] = *(const short8*)&s_u[gidx128(16 * (2 * wm + nst) + lr, ks * 4 + lq)];
        #pragma unroll
        for (int tg = 0; tg < 3; ++tg) {
          short8 a = GFRAG(ihg, gidx128(16 * tg + lr, ks * 4 + lq));
          #pragma unroll
          for (int nst = 0; nst < 2; ++nst)
            gi[tg][nst] = MFMA16(a, bb[nst], gi[tg][nst]);
        }
      }
      #pragma unroll
      for (int ks = 0; ks < 4; ++ks) {
        #pragma unroll
        for (int tg = 0; tg < 3; ++tg) {
          short8 a = GFRAG(hhg, gidx128(16 * tg + lr, ks * 4 + lq));
          #pragma unroll
          for (int nst = 0; nst < 2; ++nst)
            gh[tg][nst] = MFMA16(a, cur[nst][ks], gh[tg][nst]);
        }
      }
      __builtin_amdgcn_s_setprio(0);
      #pragma unroll
      for (int nst = 0; nst < 2; ++nst) {
        int node = 16 * (2 * wm + nst) + lr;
        float hf[4];
        #pragma unroll
        for (int r = 0; r < 4; ++r) {
          int mH = 16 * cc + 4 * lq + r;
          float rg = sigm(gi[0][nst][r] + s_bias[512 + mH] + gh[0][nst][r] + s_bias[896 + mH]);
          float zg = sigm(gi[1][nst][r] + s_bias[640 + mH] + gh[1][nst][r] + s_bias[1024 + mH]);
          float ng = tanh_(gi[2][nst][r] + s_bias[768 + mH] + rg * (gh[2][nst][r] + s_bias[1152 + mH]));
          hf[r] = (1.f - zg) * ng + zg * b2f((ushort)holdv[nst][r]);
        }
        *(u64*)((ushort*)(outb + (size_t)node * H + 64) + 16 * cc + 4 * lq) =
            pk4(hf[0], hf[1], hf[2], hf[3]);
      }
    }  // pairs
    __syncthreads();   // all h' stores drained + visible block-wide

    // ---- RELOAD (layer<2): next-layer W0/W1; cur regs from tails ----
    if (layer < 2) {
      STAGE(s_w0, wimg + (size_t)((layer + 1) * NE * 2) * IMG_GC_ELEMS, 4);
      STAGE(s_w1, wimg + (size_t)((layer + 1) * NE * 2 + 1) * IMG_GC_ELEMS, 4);
      SB0();
      #pragma unroll
      for (int mt = 0; mt < 2; ++mt)
        #pragma unroll
        for (int ks = 0; ks < 4; ++ks)
          cur[mt][ks] = *(const short8*)((const ushort*)(outb + (size_t)(32 * wm + 16 * mt + lr) * H + 64) + 32 * ks + 8 * lq);
      __syncthreads();
    }
  }  // layers
}

// ================= K3: output embedding + zero pad (unchanged) =============
__global__ __launch_bounds__(256, 2) void k_outemb(
    const float* __restrict__ out_w, const float* __restrict__ out_b,
    float* __restrict__ out)
{
  __shared__ float s_wt[H * FEAT];
  __shared__ float s_c[64 * 132];
  const int t = threadIdx.x;
  const int n = blockIdx.x >> 6, bt = blockIdx.x & 63, b0 = bt * 64;
  const float* wsrc = out_w + (size_t)n * H * FEAT;
  #pragma unroll
  for (int it = 0; it < 4; ++it) {
    int i4 = t + it * 256;
    *(f32x4*)&s_wt[i4 * 4] = *(const f32x4*)&wsrc[i4 * 4];
  }
  #pragma unroll
  for (int it = 0; it < 4; ++it) {
    int idx = t + it * 256;
    int r = idx >> 4, g = idx & 15;
    const ushort* tail = (const ushort*)(out + ((size_t)(b0 + r) * NNODE + n) * H + 64);
    short8 v = *(const short8*)(tail + g * 8);
    #pragma unroll
    for (int j = 0; j < 8; ++j) s_c[r * 132 + g * 8 + j] = b2f((ushort)v[j]);
  }
  __syncthreads();
  const int d = t & 31, rq = t >> 5;
  const float bias = out_b[n * FEAT + d];
  float accs[8];
  #pragma unroll
  for (int m = 0; m < 8; ++m) {
    int r = rq + 8 * m;
    float a = bias;
    #pragma unroll 8
    for (int k = 0; k < H; ++k) a += s_c[r * 132 + k] * s_wt[k * FEAT + d];
    accs[m] = a;
  }
  #pragma unroll
  for (int m = 0; m < 8; ++m) {
    int r = rq + 8 * m;
    out[((size_t)(b0 + r) * NNODE + n) * H + d] = accs[m];
  }
  #pragma unroll
  for (int q = 0; q < 6; ++q) {
    int idx = t + q * 256;
    int r = idx / 24, c4 = idx - r * 24;
    *(f32x4*)&out[((size_t)(b0 + r) * NNODE + n) * H + FEAT + c4 * 4] =
        f32x4{0.f, 0.f, 0.f, 0.f};
  }
}

extern "C" void kernel_launch(void* const* d_in, const int* in_sizes, int n_in,
                              void* d_out, int out_size, void* d_ws, size_t ws_size,
                              hipStream_t stream) {
  const float* x     = (const float*)d_in[0];
  const float* adj   = (const float*)d_in[1];
  const float* in_w  = (const float*)d_in[2];
  const float* in_b  = (const float*)d_in[3];
  const float* out_w = (const float*)d_in[4];
  const float* out_b = (const float*)d_in[5];
  const float* gc_w  = (const float*)d_in[6];
  const float* gc_b  = (const float*)d_in[7];
  const float* w_ih  = (const float*)d_in[8];
  const float* w_hh  = (const float*)d_in[9];
  const float* b_ih  = (const float*)d_in[10];
  const float* b_hh  = (const float*)d_in[11];
  (void)in_sizes; (void)n_in; (void)out_size;
  ushort* wimg = (ushort*)d_ws;
  const bool full = ws_size >= WS_FULL;
  hipLaunchKernelGGL(k_prep, dim3(40), dim3(256), 0, stream, gc_w, w_ih, w_hh, wimg);
  if (full) {
    hipLaunchKernelGGL(k_inemb<true>, dim3(NBATCH), dim3(256), 0, stream,
                       x, in_w, in_b, adj, wimg, (float*)d_out);
    hipLaunchKernelGGL(k_main<true>, dim3(NBATCH), dim3(256), 0, stream,
                       adj, gc_b, b_ih, b_hh, wimg, (float*)d_out);
  } else {
    hipLaunchKernelGGL(k_inemb<false>, dim3(NBATCH), dim3(256), 0, stream,
                       x, in_w, in_b, adj, wimg, (float*)d_out);
    hipLaunchKernelGGL(k_main<false>, dim3(NBATCH), dim3(256), 0, stream,
                       adj, gc_b, b_ih, b_hh, wimg, (float*)d_out);
  }
  hipLaunchKernelGGL(k_outemb, dim3(NBATCH), dim3(256), 0, stream, out_w, out_b, (float*)d_out);
}

// Round 15
// 763.777 us; speedup vs baseline: 1.7643x; 1.0152x over previous
//
#include <hip/hip_runtime.h>
#include <cstdint>

#define NBATCH 4096
#define NNODE  64
#define FEAT   32
#define H      128
#define NE     4
#define NL     3

typedef __attribute__((ext_vector_type(8))) short short8;
typedef __attribute__((ext_vector_type(4))) short short4v;
typedef __attribute__((ext_vector_type(4))) float f32x4;
typedef __attribute__((ext_vector_type(2))) float f32x2;
typedef unsigned long long u64;
typedef unsigned short ushort;

// ws layout: [0,576KB) weight images; then adj bf16 images (134MB)
#define IMG_GC_ELEMS   (128 * 64)
#define IMG_GRU_ELEMS  (48 * 128)
#define IMG_GC_BYTES   (24 * IMG_GC_ELEMS * 2)
#define IMG_GRU_BYTES  (16 * IMG_GRU_ELEMS * 2)
#define WS_W_BYTES     (IMG_GC_BYTES + IMG_GRU_BYTES)
#define WIMG_SHORTS    (WS_W_BYTES / 2)
#define ADJ_IMG_ELEMS  4096
#define WS_FULL ((size_t)WS_W_BYTES + (size_t)NBATCH * NE * ADJ_IMG_ELEMS * 2)

__device__ __forceinline__ ushort f2b(float f) {
  union { float f; unsigned u; } v; v.f = f;
  unsigned u = v.u + 0x7FFFu + ((v.u >> 16) & 1u);
  return (ushort)(u >> 16);
}
__device__ __forceinline__ float b2f(ushort s) {
  union { unsigned u; float f; } v; v.u = ((unsigned)s) << 16;
  return v.f;
}
__device__ __forceinline__ unsigned cvtpk(float lo, float hi) {
  unsigned r;
  asm volatile("v_cvt_pk_bf16_f32 %0, %1, %2" : "=v"(r) : "v"(lo), "v"(hi));
  return r;
}
__device__ __forceinline__ u64 pk4(float a, float b, float c, float d) {
  return (u64)cvtpk(a, b) | ((u64)cvtpk(c, d) << 32);
}
__device__ __forceinline__ float sigm(float v) { return 1.0f / (1.0f + __expf(-v)); }
__device__ __forceinline__ float tanh_(float v) {
  v = fminf(fmaxf(v, -15.f), 15.f);
  float e = __expf(-2.f * v);
  return (1.f - e) / (1.f + e);
}
__device__ __forceinline__ int gidx128(int r, int g) { return r * 128 + ((g ^ (r & 7)) << 3); }
__device__ __forceinline__ int idx128(int r, int k) { return gidx128(r, k >> 3) + (k & 7); }
__device__ __forceinline__ int gidx64(int r, int g) { return r * 64 + (((g ^ (r & 7)) & 7) << 3); }

__device__ __forceinline__ short8 pack8f(const float* v) {
  union { unsigned u[4]; short8 s; } r;
  r.u[0] = cvtpk(v[0], v[1]); r.u[1] = cvtpk(v[2], v[3]);
  r.u[2] = cvtpk(v[4], v[5]); r.u[3] = cvtpk(v[6], v[7]);
  return r.s;
}

__device__ __forceinline__ void gll16(const void* g, void* l) {
  __builtin_amdgcn_global_load_lds(
      (const __attribute__((address_space(1))) unsigned int*)g,
      (__attribute__((address_space(3))) unsigned int*)l, 16, 0, 0);
}

#define STAGE(dst, src, NIT)                                             \
  do {                                                                   \
    _Pragma("unroll")                                                    \
    for (int it_ = 0; it_ < (NIT); ++it_) {                              \
      int off_ = (it_ * 4 + w) * 1024;                                   \
      gll16((const char*)(src) + off_ + lane * 16, (char*)(dst) + off_); \
    }                                                                    \
  } while (0)

#define BAR() do { asm volatile("s_waitcnt lgkmcnt(0)" ::: "memory"); \
                   __builtin_amdgcn_s_barrier(); } while (0)
#define VMW(N) do { asm volatile("s_waitcnt vmcnt(" #N ")" ::: "memory"); \
                    __builtin_amdgcn_sched_barrier(0); } while (0)
#define SB0() __builtin_amdgcn_sched_barrier(0)

// ============ K0: bf16 weight images (swizzled LDS byte order) ========
__global__ __launch_bounds__(256, 2) void k_prep(
    const float* __restrict__ gc_w, const float* __restrict__ w_ih,
    const float* __restrict__ w_hh, ushort* __restrict__ ws)
{
  const int t = threadIdx.x;
  if (blockIdx.x < 24) {
    const int blk = blockIdx.x;
    const int kh = blk & 1, e = (blk >> 1) & 3, l = blk >> 3;
    const float* We = gc_w + (size_t)(l * NE + e) * H * H;
    ushort* dst = ws + (size_t)blk * IMG_GC_ELEMS;
    #pragma unroll
    for (int it = 0; it < 4; ++it) {
      int idx = t + it * 256;
      int r = idx >> 3, g = idx & 7;
      float v[8];
      #pragma unroll
      for (int j = 0; j < 8; ++j) v[j] = We[(kh * 64 + g * 8 + j) * H + r];
      *(short8*)&dst[gidx64(r, g)] = pack8f(v);
    }
  } else {
    const int blk = blockIdx.x - 24;
    const int c = blk & 7, m = blk >> 3;
    const float* Mat = m ? w_hh : w_ih;
    ushort* dst = ws + WIMG_SHORTS - IMG_GRU_BYTES / 2 + (size_t)blk * IMG_GRU_ELEMS;
    #pragma unroll
    for (int it = 0; it < 3; ++it) {
      int idx = t + it * 256;
      int rr = idx >> 4, g = idx & 15;
      int mrow = (rr >> 4) * H + 16 * c + (rr & 15);
      float v[8];
      #pragma unroll
      for (int j = 0; j < 8; ++j) v[j] = Mat[mrow * H + g * 8 + j];
      *(short8*)&dst[gidx128(rr, g)] = pack8f(v);
    }
  }
}

// ============ K1: input embedding -> bf16 h0 tails; adj->bf16 images ==========
template <bool ADJIMG>
__global__ __launch_bounds__(256, 2) void k_inemb(
    const float* __restrict__ x, const float* __restrict__ in_w,
    const float* __restrict__ in_b, const float* __restrict__ adj,
    ushort* __restrict__ ws, float* __restrict__ out)
{
  __shared__ float s_wt[FEAT * H];
  __shared__ float s_x[64 * FEAT];
  const int t = threadIdx.x;
  const int n = blockIdx.x >> 6, bt = blockIdx.x & 63, b0 = bt * 64;
  const float* wsrc = in_w + (size_t)n * FEAT * H;
  #pragma unroll
  for (int it = 0; it < 4; ++it) {
    int i4 = t + it * 256;
    *(f32x4*)&s_wt[i4 * 4] = *(const f32x4*)&wsrc[i4 * 4];
  }
  {
    int r = t >> 2, q = t & 3;
    const float* xs = x + ((size_t)(b0 + r) * NNODE + n) * FEAT;
    *(f32x4*)&s_x[r * 32 + q * 8]     = *(const f32x4*)&xs[q * 8];
    *(f32x4*)&s_x[r * 32 + q * 8 + 4] = *(const f32x4*)&xs[q * 8 + 4];
  }
  __syncthreads();
  const int h2 = t & 63, rp = t >> 6;
  const float bi0 = in_b[n * H + 2 * h2], bi1 = in_b[n * H + 2 * h2 + 1];
  #pragma unroll 1
  for (int m = 0; m < 16; ++m) {
    int r = rp + 4 * m;
    float a0 = bi0, a1 = bi1;
    #pragma unroll
    for (int d = 0; d < 32; ++d) {
      float xv = s_x[r * 32 + d];
      f32x2 wv = *(const f32x2*)&s_wt[d * H + 2 * h2];
      a0 += xv * wv.x; a1 += xv * wv.y;
    }
    unsigned p = cvtpk(a0, a1);
    ushort* tail = (ushort*)(out + ((size_t)(b0 + r) * NNODE + n) * H + 64);
    *(unsigned*)(tail + 2 * h2) = p;
  }
  if (ADJIMG) {
    const float* ab = adj + (size_t)blockIdx.x * NE * NNODE * NNODE;
    ushort* dst = ws + WIMG_SHORTS + (size_t)blockIdx.x * NE * ADJ_IMG_ELEMS;
    #pragma unroll 1
    for (int q = 0; q < 8; ++q) {
      int gi = t + q * 256;
      int e = gi >> 9, idx = gi & 511, r = idx >> 3, g = idx & 7;
      const float* src = ab + e * 4096 + r * 64 + g * 8;
      float v[8];
      #pragma unroll
      for (int j = 0; j < 8; ++j) v[j] = src[j];
      *(short8*)&dst[e * ADJ_IMG_ELEMS + gidx64(r, g)] = pack8f(v);
    }
  }
}

// ================= K2: RGCN+GRU, register-hidden + B-reuse tiling (R8 best) =============
template <bool ADJIMG>
__global__ __launch_bounds__(256, 2) void k_main(
    const float* __restrict__ adj,
    const float* __restrict__ gc_b,
    const float* __restrict__ b_ih, const float* __restrict__ b_hh,
    const ushort* __restrict__ wimg,
    float* __restrict__ out)
{
  __shared__ ushort s_u[128 * 64];      // S^T [h][j] / xf [i][h]  (16KB)
  __shared__ ushort s_stage[24576];     // 48KB union: edges{w0,w1,adj} / GRU{ih-pair,hh-pair}
  __shared__ float s_bias[1280];

  ushort* w0    = s_stage;              // 16KB
  ushort* w1    = s_stage + 8192;       // 16KB
  ushort* sadj  = s_stage + 16384;      // 8KB
  ushort* gru0  = s_stage;              // ih pair: [0,12288)
  ushort* gru1  = s_stage + 12288;      // hh pair: [12288,24576)

  const int t = threadIdx.x;
  const int b = blockIdx.x;
  const int w = t >> 6, lane = t & 63, lr = lane & 15, lq = lane >> 4;
  const int wm = w & 1, wn = w >> 1;    // M-half, N-half of this wave
  float* outb = out + (size_t)b * NNODE * H;
  const ushort* img_gru = wimg + WIMG_SHORTS - IMG_GRU_BYTES / 2;
  const ushort* aimg = wimg + WIMG_SHORTS + (size_t)b * NE * ADJ_IMG_ELEMS;

  // ---- prologue: W(l0,e0,kh0)->w0; hidden h0 -> registers; GRU biases ----
  STAGE(w0, wimg, 4);
  short8 cur[2][4];   // [row-tile][kstep]: rows 32*wm+16*rt+lr, k = 32*ks+8*lq..
  #pragma unroll
  for (int rt = 0; rt < 2; ++rt)
    #pragma unroll
    for (int ks = 0; ks < 4; ++ks) {
      int node = 32 * wm + 16 * rt + lr;
      cur[rt][ks] = *(const short8*)((const ushort*)(outb + (size_t)node * H + 64) + 32 * ks + 8 * lq);
    }
  #pragma unroll
  for (int it = 0; it < 3; ++it) {
    int idx = t + it * 256;
    s_bias[512 + idx] = (idx < 384) ? b_ih[idx] : b_hh[idx - 384];
  }
  __syncthreads();

  #pragma unroll 1
  for (int layer = 0; layer < NL; ++layer) {
    f32x4 agg[2][4];
    #pragma unroll
    for (int mt = 0; mt < 2; ++mt)
      #pragma unroll
      for (int nt = 0; nt < 4; ++nt) agg[mt][nt] = f32x4{0.f, 0.f, 0.f, 0.f};

    // ======== edges ====
    #pragma unroll 1
    for (int e = 0; e < NE; ++e) {
      const ushort* img_e = wimg + (size_t)((layer * NE + e) * 2) * IMG_GC_ELEMS;

      // ---- P2: stage W-kh1 + adj; mm1-kh0 (A from regs, B from w0) ----
      if (e == 0) {
        s_bias[t]       = gc_b[layer * 512 + t];
        s_bias[t + 256] = gc_b[layer * 512 + t + 256];
      }
      STAGE(w1, img_e + IMG_GC_ELEMS, 4);
      SB0();
      if (ADJIMG) {
        STAGE(sadj, aimg + (size_t)e * ADJ_IMG_ELEMS, 2);
        SB0();
      } else {
        const float* adj_e = adj + (((size_t)b * NE + e) * NNODE * NNODE);
        #pragma unroll
        for (int it = 0; it < 2; ++it) {
          int idx = t + it * 256;
          int i = idx >> 3, g = idx & 7;
          const float* src = adj_e + i * 64 + g * 8;
          float v[8];
          #pragma unroll
          for (int j = 0; j < 8; ++j) v[j] = src[j];
          *(short8*)&sadj[gidx64(i, g)] = pack8f(v);
        }
      }
      f32x4 Sacc[2][4];
      #pragma unroll
      for (int mt = 0; mt < 2; ++mt)
        #pragma unroll
        for (int nt = 0; nt < 4; ++nt) Sacc[mt][nt] = f32x4{0.f, 0.f, 0.f, 0.f};
      if (ADJIMG) VMW(6);               // w0 drained (6 just-issued may fly)
      __builtin_amdgcn_s_setprio(1);
      #pragma unroll
      for (int ks = 0; ks < 2; ++ks) {
        #pragma unroll
        for (int nt = 0; nt < 4; ++nt) {
          short8 bb = *(const short8*)&w0[gidx64(64 * wn + 16 * nt + lr, ks * 4 + lq)];
          #pragma unroll
          for (int mt = 0; mt < 2; ++mt)
            Sacc[mt][nt] = __builtin_amdgcn_mfma_f32_16x16x32_bf16(cur[mt][ks], bb, Sacc[mt][nt], 0, 0, 0);
        }
      }
      __builtin_amdgcn_s_setprio(0);
      if (ADJIMG) { VMW(2); BAR(); } else __syncthreads();

      // ---- P3: stage next (W-kh0' | GRU-ih0); mm1-kh1 (B from w1); pack S^T ----
      if (e < 3) { STAGE(w0, img_e + 2 * IMG_GC_ELEMS, 4); }
      else       { STAGE(gru0, img_gru, 3); }              // ih(0)
      SB0();
      __builtin_amdgcn_s_setprio(1);
      #pragma unroll
      for (int ks = 0; ks < 2; ++ks) {
        #pragma unroll
        for (int nt = 0; nt < 4; ++nt) {
          short8 bb = *(const short8*)&w1[gidx64(64 * wn + 16 * nt + lr, ks * 4 + lq)];
          #pragma unroll
          for (int mt = 0; mt < 2; ++mt)
            Sacc[mt][nt] = __builtin_amdgcn_mfma_f32_16x16x32_bf16(cur[mt][2 + ks], bb, Sacc[mt][nt], 0, 0, 0);
        }
      }
      __builtin_amdgcn_s_setprio(0);
      #pragma unroll
      for (int mt = 0; mt < 2; ++mt) {
        int j0 = 32 * wm + 16 * mt + 4 * lq;
        #pragma unroll
        for (int nt = 0; nt < 4; ++nt) {
          int h = 64 * wn + 16 * nt + lr;
          *(u64*)&s_u[gidx64(h, j0 >> 3) + (j0 & 7)] =
              pk4(Sacc[mt][nt][0], Sacc[mt][nt][1], Sacc[mt][nt][2], Sacc[mt][nt][3]);
        }
      }
      if (ADJIMG) { if (e < 3) { VMW(4); } else { VMW(3); } BAR(); } else __syncthreads();

      // ---- P4: [e3: stage GRU-ih1]; mm2 (A=s_adj, B=S^T); agg += relu ----
      if (e == 3) { STAGE(gru0 + 6144, img_gru + IMG_GRU_ELEMS, 3); SB0(); }
      {
        f32x4 Oacc[2][4];
        #pragma unroll
        for (int mt = 0; mt < 2; ++mt)
          #pragma unroll
          for (int nt = 0; nt < 4; ++nt) Oacc[mt][nt] = f32x4{0.f, 0.f, 0.f, 0.f};
        __builtin_amdgcn_s_setprio(1);
        #pragma unroll
        for (int ks = 0; ks < 2; ++ks) {
          short8 a[2];
          #pragma unroll
          for (int mt = 0; mt < 2; ++mt)
            a[mt] = *(const short8*)&sadj[gidx64(32 * wm + 16 * mt + lr, ks * 4 + lq)];
          #pragma unroll
          for (int nt = 0; nt < 4; ++nt) {
            short8 bb = *(const short8*)&s_u[gidx64(64 * wn + 16 * nt + lr, ks * 4 + lq)];
            #pragma unroll
            for (int mt = 0; mt < 2; ++mt)
              Oacc[mt][nt] = __builtin_amdgcn_mfma_f32_16x16x32_bf16(a[mt], bb, Oacc[mt][nt], 0, 0, 0);
          }
        }
        __builtin_amdgcn_s_setprio(0);
        #pragma unroll
        for (int mt = 0; mt < 2; ++mt)
          #pragma unroll
          for (int nt = 0; nt < 4; ++nt) {
            float bias = s_bias[e * 128 + 64 * wn + 16 * nt + lr];
            #pragma unroll
            for (int r = 0; r < 4; ++r)
              agg[mt][nt][r] += 0.25f * fmaxf(Oacc[mt][nt][r] + bias, 0.f);
          }
      }
      if (ADJIMG) { BAR(); } else __syncthreads();
    }  // edges

    // ---- xf = agg -> s_u row-major [i][h] ----
    #pragma unroll
    for (int mt = 0; mt < 2; ++mt)
      #pragma unroll
      for (int nt = 0; nt < 4; ++nt) {
        int h = 64 * wn + 16 * nt + lr;
        #pragma unroll
        for (int r = 0; r < 4; ++r)
          s_u[idx128(32 * wm + 16 * mt + 4 * lq + r, h)] = f2b(agg[mt][nt][r]);
      }
    __syncthreads();   // drains GRU-ih pair too

    // ======== GRU: 4 pair-steps; wave: chunk cc = 2p + wn, node-half wm ====
    #pragma unroll 1
    for (int p = 0; p < 4; ++p) {
      const int cc = 2 * p + wn;
      const ushort* ihb = gru0 + wn * 6144;
      const ushort* hhb = gru1 + wn * 6144;
      // stage hh pair; old-h loads (covered by gi)
      STAGE(gru1, img_gru + (size_t)(8 + 2 * p) * IMG_GRU_ELEMS, 3);
      STAGE(gru1 + 6144, img_gru + (size_t)(8 + 2 * p + 1) * IMG_GRU_ELEMS, 3);
      SB0();
      short4v holdv[2];
      #pragma unroll
      for (int nst = 0; nst < 2; ++nst) {
        int node = 16 * (2 * wm + nst) + lr;
        holdv[nst] = *(const short4v*)((const ushort*)(outb + (size_t)node * H + 64) + 16 * cc + 4 * lq);
      }
      f32x4 gi[3][2];
      #pragma unroll
      for (int tg = 0; tg < 3; ++tg)
        #pragma unroll
        for (int nst = 0; nst < 2; ++nst) gi[tg][nst] = f32x4{0.f, 0.f, 0.f, 0.f};
      __builtin_amdgcn_s_setprio(1);
      #pragma unroll
      for (int ks = 0; ks < 4; ++ks) {
        short8 bb[2];
        #pragma unroll
        for (int nst = 0; nst < 2; ++nst)
          bb[nst] = *(const short8*)&s_u[gidx128(16 * (2 * wm + nst) + lr, ks * 4 + lq)];
        #pragma unroll
        for (int tg = 0; tg < 3; ++tg) {
          short8 a = *(const short8*)&ihb[gidx128(16 * tg + lr, ks * 4 + lq)];
          #pragma unroll
          for (int nst = 0; nst < 2; ++nst)
            gi[tg][nst] = __builtin_amdgcn_mfma_f32_16x16x32_bf16(a, bb[nst], gi[tg][nst], 0, 0, 0);
        }
      }
      __builtin_amdgcn_s_setprio(0);
      __syncthreads();   // hh pair + old-h drained

      if (p < 3) {
        STAGE(gru0, img_gru + (size_t)(2 * (p + 1)) * IMG_GRU_ELEMS, 3);
        STAGE(gru0 + 6144, img_gru + (size_t)(2 * (p + 1) + 1) * IMG_GRU_ELEMS, 3);
      } else if (layer < 2) {
        STAGE(w0, wimg + (size_t)((layer + 1) * NE * 2) * IMG_GC_ELEMS, 4);
      }
      SB0();
      f32x4 gh[3][2];
      #pragma unroll
      for (int tg = 0; tg < 3; ++tg)
        #pragma unroll
        for (int nst = 0; nst < 2; ++nst) gh[tg][nst] = f32x4{0.f, 0.f, 0.f, 0.f};
      __builtin_amdgcn_s_setprio(1);
      #pragma unroll
      for (int ks = 0; ks < 4; ++ks) {
        #pragma unroll
        for (int tg = 0; tg < 3; ++tg) {
          short8 a = *(const short8*)&hhb[gidx128(16 * tg + lr, ks * 4 + lq)];
          #pragma unroll
          for (int nst = 0; nst < 2; ++nst)
            gh[tg][nst] = __builtin_amdgcn_mfma_f32_16x16x32_bf16(a, cur[nst][ks], gh[tg][nst], 0, 0, 0);
        }
      }
      __builtin_amdgcn_s_setprio(0);
      #pragma unroll
      for (int nst = 0; nst < 2; ++nst) {
        int node = 16 * (2 * wm + nst) + lr;
        float hf[4];
        #pragma unroll
        for (int r = 0; r < 4; ++r) {
          int mH = 16 * cc + 4 * lq + r;
          float rg = sigm(gi[0][nst][r] + s_bias[512 + mH] + gh[0][nst][r] + s_bias[896 + mH]);
          float zg = sigm(gi[1][nst][r] + s_bias[640 + mH] + gh[1][nst][r] + s_bias[1024 + mH]);
          float ng = tanh_(gi[2][nst][r] + s_bias[768 + mH] + rg * (gh[2][nst][r] + s_bias[1152 + mH]));
          float hold = b2f((ushort)holdv[nst][r]);
          hf[r] = (1.f - zg) * ng + zg * hold;
        }
        *(u64*)((ushort*)(outb + (size_t)node * H + 64) + 16 * cc + 4 * lq) =
            pk4(hf[0], hf[1], hf[2], hf[3]);
      }
      __syncthreads();   // h' writes drained; gh reads closed
    }  // pairs

    // ---- reload hidden regs from tails (block-private lines, L2-hot) ----
    if (layer < 2) {
      #pragma unroll
      for (int rt = 0; rt < 2; ++rt)
        #pragma unroll
        for (int ks = 0; ks < 4; ++ks) {
          int node = 32 * wm + 16 * rt + lr;
          cur[rt][ks] = *(const short8*)((const ushort*)(outb + (size_t)node * H + 64) + 32 * ks + 8 * lq);
        }
    }
  }  // layers
}

// ================= K3: output embedding + zero pad =============
__global__ __launch_bounds__(256, 2) void k_outemb(
    const float* __restrict__ out_w, const float* __restrict__ out_b,
    float* __restrict__ out)
{
  __shared__ float s_wt[H * FEAT];
  __shared__ float s_c[64 * 132];
  const int t = threadIdx.x;
  const int n = blockIdx.x >> 6, bt = blockIdx.x & 63, b0 = bt * 64;
  const float* wsrc = out_w + (size_t)n * H * FEAT;
  #pragma unroll
  for (int it = 0; it < 4; ++it) {
    int i4 = t + it * 256;
    *(f32x4*)&s_wt[i4 * 4] = *(const f32x4*)&wsrc[i4 * 4];
  }
  #pragma unroll
  for (int it = 0; it < 4; ++it) {
    int idx = t + it * 256;
    int r = idx >> 4, g = idx & 15;
    const ushort* tail = (const ushort*)(out + ((size_t)(b0 + r) * NNODE + n) * H + 64);
    short8 v = *(const short8*)(tail + g * 8);
    #pragma unroll
    for (int j = 0; j < 8; ++j) s_c[r * 132 + g * 8 + j] = b2f((ushort)v[j]);
  }
  __syncthreads();
  const int d = t & 31, rq = t >> 5;
  const float bias = out_b[n * FEAT + d];
  float accs[8];
  #pragma unroll
  for (int m = 0; m < 8; ++m) {
    int r = rq + 8 * m;
    float a = bias;
    #pragma unroll 8
    for (int k = 0; k < H; ++k) a += s_c[r * 132 + k] * s_wt[k * FEAT + d];
    accs[m] = a;
  }
  #pragma unroll
  for (int m = 0; m < 8; ++m) {
    int r = rq + 8 * m;
    out[((size_t)(b0 + r) * NNODE + n) * H + d] = accs[m];
  }
  #pragma unroll
  for (int q = 0; q < 6; ++q) {
    int idx = t + q * 256;
    int r = idx / 24, c4 = idx - r * 24;
    *(f32x4*)&out[((size_t)(b0 + r) * NNODE + n) * H + FEAT + c4 * 4] =
        f32x4{0.f, 0.f, 0.f, 0.f};
  }
}

extern "C" void kernel_launch(void* const* d_in, const int* in_sizes, int n_in,
                              void* d_out, int out_size, void* d_ws, size_t ws_size,
                              hipStream_t stream) {
  const float* x     = (const float*)d_in[0];
  const float* adj   = (const float*)d_in[1];
  const float* in_w  = (const float*)d_in[2];
  const float* in_b  = (const float*)d_in[3];
  const float* out_w = (const float*)d_in[4];
  const float* out_b = (const float*)d_in[5];
  const float* gc_w  = (const float*)d_in[6];
  const float* gc_b  = (const float*)d_in[7];
  const float* w_ih  = (const float*)d_in[8];
  const float* w_hh  = (const float*)d_in[9];
  const float* b_ih  = (const float*)d_in[10];
  const float* b_hh  = (const float*)d_in[11];
  (void)in_sizes; (void)n_in; (void)out_size;
  ushort* wimg = (ushort*)d_ws;
  const bool full = ws_size >= WS_FULL;
  hipLaunchKernelGGL(k_prep, dim3(40), dim3(256), 0, stream, gc_w, w_ih, w_hh, wimg);
  if (full) {
    hipLaunchKernelGGL(k_inemb<true>, dim3(NBATCH), dim3(256), 0, stream,
                       x, in_w, in_b, adj, wimg, (float*)d_out);
    hipLaunchKernelGGL(k_main<true>, dim3(NBATCH), dim3(256), 0, stream,
                       adj, gc_b, b_ih, b_hh, wimg, (float*)d_out);
  } else {
    hipLaunchKernelGGL(k_inemb<false>, dim3(NBATCH), dim3(256), 0, stream,
                       x, in_w, in_b, adj, wimg, (float*)d_out);
    hipLaunchKernelGGL(k_main<false>, dim3(NBATCH), dim3(256), 0, stream,
                       adj, gc_b, b_ih, b_hh, wimg, (float*)d_out);
  }
  hipLaunchKernelGGL(k_outemb, dim3(NBATCH), dim3(256), 0, stream, out_w, out_b, (float*)d_out);
}